// Round 7
// baseline (112.279 us; speedup 1.0000x reference)
//
#include <hip/hip_runtime.h>

#define B_  8
#define S_  1024
#define E_  512
#define TI  128
#define TJ  32
#define P_STR 40   // halves; rows 80B -> b64/b128 aligned, 4-way bank groups

typedef _Float16 half_t;
typedef _Float16 half4_t __attribute__((ext_vector_type(4)));
typedef _Float16 half8_t __attribute__((ext_vector_type(8)));
typedef float    floatx16 __attribute__((ext_vector_type(16)));

// ---------- precompute 1: Phi table [bh][j][ L[16] | H[16] ] (f16, 4 MiB) ----
// L[kk] = prod_{w<4} trig_w, H[kk] = prod_{w>=4} trig_w; score=(Li.Lj)(Hi.Hj)
__global__ __launch_bounds__(256) void phi_kernel(const float* __restrict__ x,
                                                  half_t* __restrict__ phi) {
    int idx = blockIdx.x * 256 + threadIdx.x;   // bh*1024 + j
    int bh = idx >> 10, j = idx & 1023;
    int b = bh >> 3, h = bh & 7;
    const float* px = x + ((size_t)(b * S_ + j)) * E_ + h * 64;
    float4 w0 = ((const float4*)px)[0];
    float4 w1 = ((const float4*)px)[1];
    float xi[8] = {w0.x, w0.y, w0.z, w0.w, w1.x, w1.y, w1.z, w1.w};
    float c[8], s[8];
    #pragma unroll
    for (int w = 0; w < 8; ++w) {
        float v = xi[w] * 0.5f;
        c[w] = __cosf(v);
        s[w] = __sinf(v);
    }
    float p01[4] = {c[0]*c[1], s[0]*c[1], c[0]*s[1], s[0]*s[1]};
    float p23[4] = {c[2]*c[3], s[2]*c[3], c[2]*s[3], s[2]*s[3]};
    float p45[4] = {c[4]*c[5], s[4]*c[5], c[4]*s[5], s[4]*s[5]};
    float p67[4] = {c[6]*c[7], s[6]*c[7], c[6]*s[7], s[6]*s[7]};
    half_t o[32];
    #pragma unroll
    for (int kk = 0; kk < 16; ++kk) {
        o[kk]      = (half_t)(p01[kk & 3] * p23[kk >> 2]);
        o[16 + kk] = (half_t)(p45[kk & 3] * p67[kk >> 2]);
    }
    half8_t* dst = (half8_t*)(phi + (size_t)idx * 32);
    dst[0] = *(half8_t*)&o[0];
    dst[1] = *(half8_t*)&o[8];
    dst[2] = *(half8_t*)&o[16];
    dst[3] = *(half8_t*)&o[24];
}

// ---------- precompute 2: V^T table [bh][d][j] (f16, 8 MiB) ----------------
__global__ __launch_bounds__(256) void vt_kernel(const float* __restrict__ x,
                                                 half_t* __restrict__ vt) {
    int bh = blockIdx.x >> 5, j0 = (blockIdx.x & 31) * 32;
    int b = bh >> 3, h = bh & 7;
    int t = threadIdx.x;
    __shared__ half_t sh[64 * P_STR];
    int jj = t >> 3, lo = t & 7, d0 = lo * 8;
    const float* src = x + ((size_t)(b * S_ + j0 + jj)) * E_ + h * 64 + d0;
    float4 a = ((const float4*)src)[0];
    float4 cc = ((const float4*)src)[1];
    float vals[8] = {a.x, a.y, a.z, a.w, cc.x, cc.y, cc.z, cc.w};
    #pragma unroll
    for (int nq = 0; nq < 8; ++nq) {
        int q = (nq + lo) & 7;
        sh[(d0 + q) * P_STR + jj] = (half_t)vals[q];
    }
    __syncthreads();
    int d = t >> 2, seg = t & 3;
    half8_t v = *(half8_t*)&sh[d * P_STR + seg * 8];
    *(half8_t*)(vt + ((size_t)(bh * 64 + d)) * 1024 + j0 + seg * 8) = v;
}

// ---------- main: barrier-free K-loop, frags direct from L2 ----------------
__global__ __launch_bounds__(256, 2) void attn_phi_kernel(const half_t* __restrict__ phi,
                                                          const half_t* __restrict__ vt,
                                                          float* __restrict__ out) {
    const int bh = blockIdx.x;
    const int b  = bh >> 3, h = bh & 7;
    const int i0 = blockIdx.y * TI;
    const int t  = threadIdx.x;
    const int wv = t >> 6;
    const int ln = t & 63;
    const int m  = ln & 31;
    const int hf = ln >> 5;

    __shared__ __align__(16) half_t sh_p[TI * P_STR];
    __shared__ float sh_den[TI];

    const half_t* phibh = phi + (size_t)bh * (1024 * 32);
    const half_t* vtbh  = vt  + (size_t)bh * (64 * 1024);

    // B-side fragments (Phi_i), i = i0 + wv*32 + m
    const half_t* pi = phibh + (size_t)(i0 + wv * 32 + m) * 32 + hf * 8;
    half8_t biL = *(const half8_t*)pi;
    half8_t biH = *(const half8_t*)(pi + 16);

    floatx16 acc0, acc1, z;
    #pragma unroll
    for (int k = 0; k < 16; ++k) { acc0[k] = 0.f; acc1[k] = 0.f; z[k] = 0.f; }
    float dacc0 = 0.f, dacc1 = 0.f;

    const int irow = wv * 32 + m;
    const half_t* prow = &sh_p[irow * P_STR];

    // prefetch tile 0
    const half_t* pj  = phibh + (size_t)m * 32 + hf * 8;
    const half_t* v0p = vtbh + (size_t)m * 1024 + hf * 8;
    const half_t* v1p = vtbh + (size_t)(32 + m) * 1024 + hf * 8;
    half8_t ajL = *(const half8_t*)pj;
    half8_t ajH = *(const half8_t*)(pj + 16);
    half8_t b00 = *(const half8_t*)v0p;
    half8_t b01 = *(const half8_t*)(v0p + 16);
    half8_t b10 = *(const half8_t*)v1p;
    half8_t b11 = *(const half8_t*)(v1p + 16);

    for (int j0 = 0; j0 < S_; j0 += TJ) {
        // issue next tile's loads (wrap harmlessly on last iter)
        int jn = (j0 + TJ) & (S_ - 1);
        const half_t* pjn  = phibh + (size_t)(jn + m) * 32 + hf * 8;
        const half_t* v0pn = vtbh + (size_t)m * 1024 + jn + hf * 8;
        const half_t* v1pn = vtbh + (size_t)(32 + m) * 1024 + jn + hf * 8;
        half8_t najL = *(const half8_t*)pjn;
        half8_t najH = *(const half8_t*)(pjn + 16);
        half8_t nb00 = *(const half8_t*)v0pn;
        half8_t nb01 = *(const half8_t*)(v0pn + 16);
        half8_t nb10 = *(const half8_t*)v1pn;
        half8_t nb11 = *(const half8_t*)(v1pn + 16);

        // scores (transposed): lane holds S^T[j][i=wv*32+m]
        floatx16 sH = __builtin_amdgcn_mfma_f32_32x32x16_f16(ajH, biH, z, 0, 0, 0);
        floatx16 sL = __builtin_amdgcn_mfma_f32_32x32x16_f16(ajL, biL, z, 0, 0, 0);

        // exp|s| -> f16 P[i][j] in LDS (own-wave rows; same-wave LDS is ordered)
        #pragma unroll
        for (int g = 0; g < 4; ++g) {
            half4_t pk;
            #pragma unroll
            for (int r = 0; r < 4; ++r) {
                float sc = sH[4 * g + r] * sL[4 * g + r];
                float p = __expf(__builtin_fabsf(sc));
                if (r & 1) dacc1 += p; else dacc0 += p;
                pk[r] = (half_t)p;
            }
            *(half4_t*)&sh_p[irow * P_STR + g * 8 + hf * 4] = pk;
        }

        // PV: A = P[i][k=j], B = V^T[d][k=j]
        half8_t ap0 = *(const half8_t*)(prow + hf * 8);
        half8_t ap1 = *(const half8_t*)(prow + 16 + hf * 8);
        acc0 = __builtin_amdgcn_mfma_f32_32x32x16_f16(ap0, b00, acc0, 0, 0, 0);
        acc0 = __builtin_amdgcn_mfma_f32_32x32x16_f16(ap1, b01, acc0, 0, 0, 0);
        acc1 = __builtin_amdgcn_mfma_f32_32x32x16_f16(ap0, b10, acc1, 0, 0, 0);
        acc1 = __builtin_amdgcn_mfma_f32_32x32x16_f16(ap1, b11, acc1, 0, 0, 0);

        ajL = najL; ajH = najH;
        b00 = nb00; b01 = nb01; b10 = nb10; b11 = nb11;
    }

    float dacc = dacc0 + dacc1;
    dacc += __shfl_xor(dacc, 32, 64);
    sh_den[wv * 32 + m] = dacc;
    __syncthreads();

    #pragma unroll
    for (int reg = 0; reg < 16; ++reg) {
        int il = (reg & 3) + 8 * (reg >> 2) + 4 * hf;
        float inv = 1.f / sh_den[wv * 32 + il];
        size_t base = ((size_t)(b * S_ + i0 + wv * 32 + il)) * E_ + h * 64 + m;
        out[base]      = acc0[reg] * inv;
        out[base + 32] = acc1[reg] * inv;
    }
}

// ---------- fallback (R6 kernel) if workspace were too small ---------------
__device__ __forceinline__ void make_frags_fb(float4 w0, float4 w1, int hf,
                                              half8_t* fH, half8_t* fL) {
    float xi[8] = {w0.x, w0.y, w0.z, w0.w, w1.x, w1.y, w1.z, w1.w};
    float c[8], s[8];
    #pragma unroll
    for (int w = 0; w < 8; ++w) {
        float v = xi[w] * 0.5f;
        c[w] = __cosf(v);
        s[w] = __sinf(v);
    }
    float p01[4] = {c[0]*c[1], s[0]*c[1], c[0]*s[1], s[0]*s[1]};
    float p23[4] = {c[2]*c[3], s[2]*c[3], c[2]*s[3], s[2]*s[3]};
    float p45[4] = {c[4]*c[5], s[4]*c[5], c[4]*s[5], s[4]*s[5]};
    float p67[4] = {c[6]*c[7], s[6]*c[7], c[6]*s[7], s[6]*s[7]};
    #pragma unroll
    for (int idx = 0; idx < 8; ++idx) {
        int a = idx & 3;
        int bsel = (idx >> 2) | (hf << 1);
        (*fL)[idx] = (half_t)(p01[a] * p23[bsel]);
        (*fH)[idx] = (half_t)(p45[a] * p67[bsel]);
    }
}

__global__ __launch_bounds__(256, 2) void attn_fb_kernel(const float* __restrict__ x,
                                                         float* __restrict__ out) {
    const int bh = blockIdx.x;
    const int b  = bh >> 3, h = bh & 7;
    const int i0 = blockIdx.y * TI;
    const int t  = threadIdx.x;
    const int wv = t >> 6, ln = t & 63, m = ln & 31, hf = ln >> 5, lo = t & 7;
    __shared__ __align__(16) half_t sh_p[TI * P_STR];
    __shared__ __align__(16) half_t sh_v[64 * P_STR];
    __shared__ float sh_den[TI];
    const float* xh = x + (size_t)b * S_ * E_ + h * 64;
    half8_t biH, biL;
    {
        const float* px = xh + (size_t)(i0 + wv * 32 + m) * E_;
        make_frags_fb(((const float4*)px)[0], ((const float4*)px)[1], hf, &biH, &biL);
    }
    floatx16 acc0, acc1, z;
    #pragma unroll
    for (int k = 0; k < 16; ++k) { acc0[k] = 0.f; acc1[k] = 0.f; z[k] = 0.f; }
    float dacc = 0.f;
    const int sv_j = t >> 3, sv_d0 = lo * 8;
    for (int j0 = 0; j0 < S_; j0 += TJ) {
        __syncthreads();
        const float* pjx = xh + (size_t)(j0 + m) * E_;
        float4 jw0 = ((const float4*)pjx)[0];
        float4 jw1 = ((const float4*)pjx)[1];
        const float* pv = xh + (size_t)(j0 + sv_j) * E_ + sv_d0;
        float4 v0 = ((const float4*)pv)[0];
        float4 v1 = ((const float4*)pv)[1];
        half8_t ajH, ajL;
        make_frags_fb(jw0, jw1, hf, &ajH, &ajL);
        {
            float vals[8] = {v0.x, v0.y, v0.z, v0.w, v1.x, v1.y, v1.z, v1.w};
            #pragma unroll
            for (int nq = 0; nq < 8; ++nq) {
                int q = (nq + lo) & 7;
                sh_v[(sv_d0 + q) * P_STR + sv_j] = (half_t)vals[q];
            }
        }
        __syncthreads();
        floatx16 sH = __builtin_amdgcn_mfma_f32_32x32x16_f16(ajH, biH, z, 0, 0, 0);
        floatx16 sL = __builtin_amdgcn_mfma_f32_32x32x16_f16(ajL, biL, z, 0, 0, 0);
        const int irow = wv * 32 + m;
        #pragma unroll
        for (int g = 0; g < 4; ++g) {
            half4_t pk;
            #pragma unroll
            for (int r = 0; r < 4; ++r) {
                float sc = sH[4 * g + r] * sL[4 * g + r];
                float p = __expf(__builtin_fabsf(sc));
                dacc += p;
                pk[r] = (half_t)p;
            }
            *(half4_t*)&sh_p[irow * P_STR + g * 8 + hf * 4] = pk;
        }
        const half_t* prow = &sh_p[(wv * 32 + m) * P_STR];
        half8_t ap0 = *(const half8_t*)(prow + hf * 8);
        half8_t ap1 = *(const half8_t*)(prow + 16 + hf * 8);
        const half_t* vr0 = &sh_v[m * P_STR];
        const half_t* vr1 = &sh_v[(32 + m) * P_STR];
        half8_t b00 = *(const half8_t*)(vr0 + hf * 8);
        half8_t b01 = *(const half8_t*)(vr0 + 16 + hf * 8);
        half8_t b10 = *(const half8_t*)(vr1 + hf * 8);
        half8_t b11 = *(const half8_t*)(vr1 + 16 + hf * 8);
        acc0 = __builtin_amdgcn_mfma_f32_32x32x16_f16(ap0, b00, acc0, 0, 0, 0);
        acc0 = __builtin_amdgcn_mfma_f32_32x32x16_f16(ap1, b01, acc0, 0, 0, 0);
        acc1 = __builtin_amdgcn_mfma_f32_32x32x16_f16(ap0, b10, acc1, 0, 0, 0);
        acc1 = __builtin_amdgcn_mfma_f32_32x32x16_f16(ap1, b11, acc1, 0, 0, 0);
    }
    dacc += __shfl_xor(dacc, 32, 64);
    sh_den[wv * 32 + m] = dacc;
    __syncthreads();
    #pragma unroll
    for (int reg = 0; reg < 16; ++reg) {
        int il = (reg & 3) + 8 * (reg >> 2) + 4 * hf;
        float inv = 1.f / sh_den[wv * 32 + il];
        size_t base = ((size_t)(b * S_ + i0 + wv * 32 + il)) * E_ + h * 64 + m;
        out[base]      = acc0[reg] * inv;
        out[base + 32] = acc1[reg] * inv;
    }
}

extern "C" void kernel_launch(void* const* d_in, const int* in_sizes, int n_in,
                              void* d_out, int out_size, void* d_ws, size_t ws_size,
                              hipStream_t stream) {
    const float* x = (const float*)d_in[0];
    float* out = (float*)d_out;
    const size_t PHI_BYTES = (size_t)64 * 1024 * 32 * sizeof(half_t);  // 4 MiB
    const size_t VT_BYTES  = (size_t)64 * 64 * 1024 * sizeof(half_t);  // 8 MiB
    if (ws_size >= PHI_BYTES + VT_BYTES) {
        half_t* phi = (half_t*)d_ws;
        half_t* vt  = (half_t*)((char*)d_ws + PHI_BYTES);
        phi_kernel<<<dim3(64 * 1024 / 256), 256, 0, stream>>>(x, phi);
        vt_kernel<<<dim3(64 * 32), 256, 0, stream>>>(x, vt);
        attn_phi_kernel<<<dim3(B_ * 8, S_ / TI), 256, 0, stream>>>(phi, vt, out);
    } else {
        attn_fb_kernel<<<dim3(B_ * 8, S_ / TI), 256, 0, stream>>>(x, out);
    }
}